// Round 1
// 655.939 us; speedup vs baseline: 1.0089x; 1.0089x over previous
//
#include <hip/hip_runtime.h>
#include <math.h>

// GlobalAttentionPooling, fused single pass, v2.
// One block (4 waves) per segment. Tile = 16 rows per block-iteration
// (wave wv owns rows tile*16 + wv*4 + {0..3}); fully branchless main loop
// (clamped row indices + -INF gate masking) with an explicit 1-deep
// prefetch double buffer so the next tile's 4 KB/wave is in flight while
// the current tile's butterfly-reduce / exp / online-softmax update runs.
// Segment offsets precomputed into d_ws (removes per-block binary search).

#define DIM 256

__device__ __forceinline__ int lower_bound(const int* __restrict__ b, int n, int key) {
    int lo = 0, hi = n;
    while (lo < hi) {
        int mid = (lo + hi) >> 1;
        if (b[mid] < key) lo = mid + 1; else hi = mid;
    }
    return lo;
}

// offs[g] = first row index i with batch[i] >= g; offs[G] = N. Handles empty segments.
__global__ void build_offsets_kernel(const int* __restrict__ batch,
                                     int* __restrict__ offs, int N, int G) {
    int i = blockIdx.x * blockDim.x + threadIdx.x;
    const int stride = gridDim.x * blockDim.x;
    for (; i < N; i += stride) {
        const int b    = batch[i];
        const int prev = (i == 0) ? -1 : batch[i - 1];
        for (int g = prev + 1; g <= b; ++g) offs[g] = i;
        if (i == N - 1) {
            for (int g = b + 1; g <= G; ++g) offs[g] = N;
        }
    }
}

__device__ __forceinline__ float dot4(const float4 a, const float4 b) {
    return fmaf(a.x, b.x, fmaf(a.y, b.y, fmaf(a.z, b.z, a.w * b.w)));
}

__global__ __launch_bounds__(256)
void gap_fused_kernel(const float* __restrict__ x,
                      const int* __restrict__ batch,
                      const float* __restrict__ Wg,
                      const float* __restrict__ bg,
                      const int* __restrict__ offs,   // may be nullptr
                      float* __restrict__ out,
                      int N) {
    const int g    = blockIdx.x;
    const int tid  = threadIdx.x;
    const int lane = tid & 63;
    const int wv   = tid >> 6;

    int start, end;
    if (offs) {
        start = offs[g];
        end   = offs[g + 1];
    } else {
        start = lower_bound(batch, N, g);
        end   = lower_bound(batch, N, g + 1);
    }

    __shared__ float s_ml[8];           // m[0..3], l[4..7]
    __shared__ float s_acc[4 * DIM];    // 4 KB

    if (start >= end) {                 // empty segment -> zeros
        out[(size_t)g * DIM + tid] = 0.0f;
        return;
    }

    const float4 wgv  = ((const float4*)Wg)[lane];   // Wg[4*lane .. 4*lane+3]
    const float  bias = bg[0];
    const int    len  = end - start;
    const float4* __restrict__ x4 = (const float4*)x + (size_t)start * (DIM / 4);

    float  m   = -INFINITY;
    float  l   = 0.0f;
    float4 acc = make_float4(0.f, 0.f, 0.f, 0.f);

    const int ntiles = (len + 15) >> 4;
    const int rb     = wv * 4;          // wave's first row inside each 16-row tile
    const int lmax   = len - 1;

    // Clamped float4 index: always in-bounds, branchless.
    auto ridx = [&](int row) -> size_t {
        const int rr = row < lmax ? row : lmax;
        return (size_t)rr * 64 + lane;
    };

    // Preload tile 0 (4 rows / wave, 4 KB / wave).
    float4 c0 = x4[ridx(rb + 0)];
    float4 c1 = x4[ridx(rb + 1)];
    float4 c2 = x4[ridx(rb + 2)];
    float4 c3 = x4[ridx(rb + 3)];

    for (int j = 0; j < ntiles; ++j) {
        const int base = j * 16 + rb;

        // ---- prefetch next tile (clamped; last-iter rereads cached tail row) ----
        const int nb = base + 16;
        float4 n0 = x4[ridx(nb + 0)];
        float4 n1 = x4[ridx(nb + 1)];
        float4 n2 = x4[ridx(nb + 2)];
        float4 n3 = x4[ridx(nb + 3)];

        // ---- gates: 4 interleaved 64-lane butterflies ----
        float d0 = dot4(c0, wgv);
        float d1 = dot4(c1, wgv);
        float d2 = dot4(c2, wgv);
        float d3 = dot4(c3, wgv);
        #pragma unroll
        for (int off = 32; off; off >>= 1) {
            d0 += __shfl_xor(d0, off);
            d1 += __shfl_xor(d1, off);
            d2 += __shfl_xor(d2, off);
            d3 += __shfl_xor(d3, off);
        }
        const bool v0 = (base + 0) < len;
        const bool v1 = (base + 1) < len;
        const bool v2 = (base + 2) < len;
        const bool v3 = (base + 3) < len;
        const float g0 = v0 ? d0 + bias : -INFINITY;
        const float g1 = v1 ? d1 + bias : -INFINITY;
        const float g2 = v2 ? d2 + bias : -INFINITY;
        const float g3 = v3 ? d3 + bias : -INFINITY;

        // ---- online softmax update (branchless, NaN-safe for all-masked tiles) ----
        const float nm    = fmaxf(m, fmaxf(fmaxf(g0, g1), fmaxf(g2, g3)));
        const float alpha = (m == nm) ? 1.0f : __expf(m - nm);   // handles m=nm=-inf
        const float p0 = v0 ? __expf(g0 - nm) : 0.0f;
        const float p1 = v1 ? __expf(g1 - nm) : 0.0f;
        const float p2 = v2 ? __expf(g2 - nm) : 0.0f;
        const float p3 = v3 ? __expf(g3 - nm) : 0.0f;
        l = fmaf(l, alpha, (p0 + p1) + (p2 + p3));
        acc.x = fmaf(p0, c0.x, fmaf(p1, c1.x, fmaf(p2, c2.x, fmaf(p3, c3.x, acc.x * alpha))));
        acc.y = fmaf(p0, c0.y, fmaf(p1, c1.y, fmaf(p2, c2.y, fmaf(p3, c3.y, acc.y * alpha))));
        acc.z = fmaf(p0, c0.z, fmaf(p1, c1.z, fmaf(p2, c2.z, fmaf(p3, c3.z, acc.z * alpha))));
        acc.w = fmaf(p0, c0.w, fmaf(p1, c1.w, fmaf(p2, c2.w, fmaf(p3, c3.w, acc.w * alpha))));
        m = nm;

        c0 = n0; c1 = n1; c2 = n2; c3 = n3;   // rotate double buffer
    }

    // ---- merge the 4 waves' states (single barrier) ----
    if (lane == 0) { s_ml[wv] = m; s_ml[4 + wv] = l; }   // m,l are wave-uniform
    ((float4*)s_acc)[wv * 64 + lane] = acc;
    __syncthreads();

    const float M = fmaxf(fmaxf(s_ml[0], s_ml[1]), fmaxf(s_ml[2], s_ml[3])); // finite
    float denom = 0.f, val = 0.f;
    #pragma unroll
    for (int w = 0; w < 4; ++w) {
        const float sc = __expf(s_ml[w] - M);            // 0 for idle waves (m=-inf)
        denom = fmaf(s_ml[4 + w], sc, denom);
        val   = fmaf(s_acc[w * DIM + tid], sc, val);
    }
    out[(size_t)g * DIM + tid] = val / denom;
}

extern "C" void kernel_launch(void* const* d_in, const int* in_sizes, int n_in,
                              void* d_out, int out_size, void* d_ws, size_t ws_size,
                              hipStream_t stream) {
    const float* x     = (const float*)d_in[0];
    const int*   batch = (const int*)d_in[1];
    const float* Wg    = (const float*)d_in[2];
    const float* bg    = (const float*)d_in[3];
    float*       out   = (float*)d_out;

    const int N = in_sizes[1];          // 500000 nodes
    const int G = out_size / DIM;       // 4096 graphs

    int* offs = nullptr;
    if (d_ws != nullptr && ws_size >= (size_t)(G + 1) * sizeof(int)) {
        offs = (int*)d_ws;
        build_offsets_kernel<<<1024, 256, 0, stream>>>(batch, offs, N, G);
    }
    gap_fused_kernel<<<G, DIM, 0, stream>>>(x, batch, Wg, bg, offs, out, N);
}

// Round 2
// 620.280 us; speedup vs baseline: 1.0669x; 1.0575x over previous
//
#include <hip/hip_runtime.h>
#include <math.h>

// GlobalAttentionPooling, fused single pass, v3.
// One block (4 waves) per segment. Tile = 32 rows/block-iteration; wave wv owns
// the CONTIGUOUS 8-row run tile*32 + wv*8 + {0..7} (8 KB contiguous per wave).
// Hot loop handles only FULL tiles: no clamping, no masking, no -INF selects;
// a single masked tail tile reuses the last prefetch. 1-deep prefetch of 8 KB
// per wave keeps 2x the previous bytes in flight; non-temporal loads avoid
// polluting L2/L3 with read-once data. __launch_bounds__(256,4) caps VGPRs at
// 128 so >=4 blocks/CU stay resident (>=128 KB in flight per CU).

#define DIM 256

typedef float f32x4 __attribute__((ext_vector_type(4)));

__device__ __forceinline__ int lower_bound(const int* __restrict__ b, int n, int key) {
    int lo = 0, hi = n;
    while (lo < hi) {
        int mid = (lo + hi) >> 1;
        if (b[mid] < key) lo = mid + 1; else hi = mid;
    }
    return lo;
}

// offs[g] = first row index i with batch[i] >= g; offs[G] = N. Handles empty segments.
__global__ void build_offsets_kernel(const int* __restrict__ batch,
                                     int* __restrict__ offs, int N, int G) {
    int i = blockIdx.x * blockDim.x + threadIdx.x;
    const int stride = gridDim.x * blockDim.x;
    for (; i < N; i += stride) {
        const int b    = batch[i];
        const int prev = (i == 0) ? -1 : batch[i - 1];
        for (int g = prev + 1; g <= b; ++g) offs[g] = i;
        if (i == N - 1) {
            for (int g = b + 1; g <= G; ++g) offs[g] = N;
        }
    }
}

__device__ __forceinline__ float dot4(const f32x4 a, const f32x4 b) {
    return fmaf(a[0], b[0], fmaf(a[1], b[1], fmaf(a[2], b[2], a[3] * b[3])));
}

__global__ __launch_bounds__(256, 4)
void gap_fused_kernel(const float* __restrict__ x,
                      const int* __restrict__ batch,
                      const float* __restrict__ Wg,
                      const float* __restrict__ bg,
                      const int* __restrict__ offs,   // may be nullptr
                      float* __restrict__ out,
                      int N) {
    const int g    = blockIdx.x;
    const int tid  = threadIdx.x;
    const int lane = tid & 63;
    const int wv   = tid >> 6;

    int start, end;
    if (offs) {
        start = offs[g];
        end   = offs[g + 1];
    } else {
        start = lower_bound(batch, N, g);
        end   = lower_bound(batch, N, g + 1);
    }

    __shared__ float s_ml[8];           // m[0..3], l[4..7]
    __shared__ float s_acc[4 * DIM];    // 4 KB

    if (start >= end) {                 // empty segment -> zeros
        out[(size_t)g * DIM + tid] = 0.0f;
        return;
    }

    const f32x4 wgv  = ((const f32x4*)Wg)[lane];     // Wg[4*lane .. 4*lane+3]
    const float bias = bg[0];
    const int   len  = end - start;
    const int   lmax = len - 1;
    const f32x4* __restrict__ xb =
        (const f32x4*)x + (size_t)start * (DIM / 4) + lane;   // lane folded in

    // Clamped, non-temporal row load (clamp only ever triggers on prefetch/tail).
    auto ld = [&](int row) -> f32x4 {
        const int rr = row < lmax ? row : lmax;
        return __builtin_nontemporal_load(xb + (size_t)rr * (DIM / 4));
    };

    float m = -INFINITY;
    float l = 0.0f;
    f32x4 acc = {0.f, 0.f, 0.f, 0.f};

    const int rb    = wv * 8;           // wave's first row inside each 32-row tile
    const int nfull = len >> 5;         // number of full 32-row tiles

    f32x4 c0, c1, c2, c3, c4, c5, c6, c7;
    bool have_c = false;

    if (nfull > 0) {
        // Preload tile 0.
        c0 = ld(rb + 0); c1 = ld(rb + 1); c2 = ld(rb + 2); c3 = ld(rb + 3);
        c4 = ld(rb + 4); c5 = ld(rb + 5); c6 = ld(rb + 6); c7 = ld(rb + 7);

        for (int j = 0; j < nfull; ++j) {
            // ---- prefetch next tile (clamped; last iter preloads the tail rows) ----
            const int nb = (j + 1) * 32 + rb;
            f32x4 n0 = ld(nb + 0), n1 = ld(nb + 1), n2 = ld(nb + 2), n3 = ld(nb + 3);
            f32x4 n4 = ld(nb + 4), n5 = ld(nb + 5), n6 = ld(nb + 6), n7 = ld(nb + 7);

            // ---- gates: 8 interleaved 64-lane butterflies (all rows valid) ----
            float d0 = dot4(c0, wgv), d1 = dot4(c1, wgv), d2 = dot4(c2, wgv), d3 = dot4(c3, wgv);
            float d4 = dot4(c4, wgv), d5 = dot4(c5, wgv), d6 = dot4(c6, wgv), d7 = dot4(c7, wgv);
            #pragma unroll
            for (int off = 32; off; off >>= 1) {
                d0 += __shfl_xor(d0, off); d1 += __shfl_xor(d1, off);
                d2 += __shfl_xor(d2, off); d3 += __shfl_xor(d3, off);
                d4 += __shfl_xor(d4, off); d5 += __shfl_xor(d5, off);
                d6 += __shfl_xor(d6, off); d7 += __shfl_xor(d7, off);
            }
            d0 += bias; d1 += bias; d2 += bias; d3 += bias;
            d4 += bias; d5 += bias; d6 += bias; d7 += bias;

            const float mx = fmaxf(fmaxf(fmaxf(d0, d1), fmaxf(d2, d3)),
                                   fmaxf(fmaxf(d4, d5), fmaxf(d6, d7)));
            const float nm    = fmaxf(m, mx);          // finite
            const float alpha = __expf(m - nm);        // 0 on first tile (m=-inf)
            const float p0 = __expf(d0 - nm), p1 = __expf(d1 - nm);
            const float p2 = __expf(d2 - nm), p3 = __expf(d3 - nm);
            const float p4 = __expf(d4 - nm), p5 = __expf(d5 - nm);
            const float p6 = __expf(d6 - nm), p7 = __expf(d7 - nm);
            l = fmaf(l, alpha, ((p0 + p1) + (p2 + p3)) + ((p4 + p5) + (p6 + p7)));
            #pragma unroll
            for (int k = 0; k < 4; ++k) {
                float a = acc[k] * alpha;
                a = fmaf(p0, c0[k], a); a = fmaf(p1, c1[k], a);
                a = fmaf(p2, c2[k], a); a = fmaf(p3, c3[k], a);
                a = fmaf(p4, c4[k], a); a = fmaf(p5, c5[k], a);
                a = fmaf(p6, c6[k], a); a = fmaf(p7, c7[k], a);
                acc[k] = a;
            }
            m = nm;

            c0 = n0; c1 = n1; c2 = n2; c3 = n3;       // rotate double buffer
            c4 = n4; c5 = n5; c6 = n6; c7 = n7;
        }
        have_c = true;   // c regs now hold (clamped) rows nfull*32 + rb + {0..7}
    }

    // ---- masked tail tile (rows nfull*32 .. len-1) ----
    const int trem = len - (nfull << 5);
    if (trem > 0) {
        const int base = (nfull << 5) + rb;
        if (!have_c) {
            c0 = ld(base + 0); c1 = ld(base + 1); c2 = ld(base + 2); c3 = ld(base + 3);
            c4 = ld(base + 4); c5 = ld(base + 5); c6 = ld(base + 6); c7 = ld(base + 7);
        }
        float d0 = dot4(c0, wgv), d1 = dot4(c1, wgv), d2 = dot4(c2, wgv), d3 = dot4(c3, wgv);
        float d4 = dot4(c4, wgv), d5 = dot4(c5, wgv), d6 = dot4(c6, wgv), d7 = dot4(c7, wgv);
        #pragma unroll
        for (int off = 32; off; off >>= 1) {
            d0 += __shfl_xor(d0, off); d1 += __shfl_xor(d1, off);
            d2 += __shfl_xor(d2, off); d3 += __shfl_xor(d3, off);
            d4 += __shfl_xor(d4, off); d5 += __shfl_xor(d5, off);
            d6 += __shfl_xor(d6, off); d7 += __shfl_xor(d7, off);
        }
        const bool v0 = (base + 0) < len, v1 = (base + 1) < len;
        const bool v2 = (base + 2) < len, v3 = (base + 3) < len;
        const bool v4 = (base + 4) < len, v5 = (base + 5) < len;
        const bool v6 = (base + 6) < len, v7 = (base + 7) < len;
        const float g0 = v0 ? d0 + bias : -INFINITY;
        const float g1 = v1 ? d1 + bias : -INFINITY;
        const float g2 = v2 ? d2 + bias : -INFINITY;
        const float g3 = v3 ? d3 + bias : -INFINITY;
        const float g4 = v4 ? d4 + bias : -INFINITY;
        const float g5 = v5 ? d5 + bias : -INFINITY;
        const float g6 = v6 ? d6 + bias : -INFINITY;
        const float g7 = v7 ? d7 + bias : -INFINITY;

        const float mx = fmaxf(fmaxf(fmaxf(g0, g1), fmaxf(g2, g3)),
                               fmaxf(fmaxf(g4, g5), fmaxf(g6, g7)));
        const float nm    = fmaxf(m, mx);
        const float alpha = (m == nm) ? 1.0f : __expf(m - nm); // safe for m=nm=-inf
        const float p0 = v0 ? __expf(g0 - nm) : 0.0f;
        const float p1 = v1 ? __expf(g1 - nm) : 0.0f;
        const float p2 = v2 ? __expf(g2 - nm) : 0.0f;
        const float p3 = v3 ? __expf(g3 - nm) : 0.0f;
        const float p4 = v4 ? __expf(g4 - nm) : 0.0f;
        const float p5 = v5 ? __expf(g5 - nm) : 0.0f;
        const float p6 = v6 ? __expf(g6 - nm) : 0.0f;
        const float p7 = v7 ? __expf(g7 - nm) : 0.0f;
        l = fmaf(l, alpha, ((p0 + p1) + (p2 + p3)) + ((p4 + p5) + (p6 + p7)));
        #pragma unroll
        for (int k = 0; k < 4; ++k) {
            float a = acc[k] * alpha;
            a = fmaf(p0, c0[k], a); a = fmaf(p1, c1[k], a);
            a = fmaf(p2, c2[k], a); a = fmaf(p3, c3[k], a);
            a = fmaf(p4, c4[k], a); a = fmaf(p5, c5[k], a);
            a = fmaf(p6, c6[k], a); a = fmaf(p7, c7[k], a);
            acc[k] = a;
        }
        m = nm;
    }

    // ---- merge the 4 waves' states (single barrier) ----
    if (lane == 0) { s_ml[wv] = m; s_ml[4 + wv] = l; }   // m,l are wave-uniform
    ((f32x4*)s_acc)[wv * 64 + lane] = acc;
    __syncthreads();

    const float M = fmaxf(fmaxf(s_ml[0], s_ml[1]), fmaxf(s_ml[2], s_ml[3])); // finite
    float denom = 0.f, val = 0.f;
    #pragma unroll
    for (int w = 0; w < 4; ++w) {
        const float sc = __expf(s_ml[w] - M);            // 0 for idle waves (m=-inf)
        denom = fmaf(s_ml[4 + w], sc, denom);
        val   = fmaf(s_acc[w * DIM + tid], sc, val);
    }
    __builtin_nontemporal_store(val / denom, &out[(size_t)g * DIM + tid]);
}

extern "C" void kernel_launch(void* const* d_in, const int* in_sizes, int n_in,
                              void* d_out, int out_size, void* d_ws, size_t ws_size,
                              hipStream_t stream) {
    const float* x     = (const float*)d_in[0];
    const int*   batch = (const int*)d_in[1];
    const float* Wg    = (const float*)d_in[2];
    const float* bg    = (const float*)d_in[3];
    float*       out   = (float*)d_out;

    const int N = in_sizes[1];          // 500000 nodes
    const int G = out_size / DIM;       // 4096 graphs

    int* offs = nullptr;
    if (d_ws != nullptr && ws_size >= (size_t)(G + 1) * sizeof(int)) {
        offs = (int*)d_ws;
        build_offsets_kernel<<<1024, 256, 0, stream>>>(batch, offs, N, G);
    }
    gap_fused_kernel<<<G, DIM, 0, stream>>>(x, batch, Wg, bg, offs, out, N);
}